// Round 1
// baseline (631.788 us; speedup 1.0000x reference)
//
#include <hip/hip_runtime.h>

#define NB 8
#define KK 20
#define XD 224
#define YD 224
#define NPIX (XD*YD)        // 50176
#define TILE 16
#define NT 14               // 224/16
#define TW 26               // TILE + 2*5 halo
#define NOFF 31
#define NKTOT (NB*KK)       // 160
#define NTILES (NT*NT)      // 196

namespace {
// offsets with sqrt(dm^2+dn^2) >= 5, dm,dn in [-5,4] (faithful to source)
constexpr int DM[NOFF] = {
  -5,-5,-5,-5,-5,-5,-5,-5,-5,-5,
  -4,-4,-4,-4,-4,
  -3,-3,-3,
  -2,-1, 0, 1, 2,
   3, 3, 3,
   4, 4, 4, 4, 4};
constexpr int DN[NOFF] = {
  -5,-4,-3,-2,-1, 0, 1, 2, 3, 4,
  -5,-4,-3, 3, 4,
  -5,-4, 4,
  -5,-5,-5,-5,-5,
  -5,-4, 4,
  -5,-4,-3, 3, 4};
}

// ---------- K1: per-batch x sums: S[n][3], s2[n] ----------
__global__ void ncuts_stats(const float* __restrict__ x,
                            float* __restrict__ Sv, float* __restrict__ s2v) {
  __shared__ float red[4][4];
  const int n = blockIdx.x, t = threadIdx.x;
  const int lane = t & 63, wv = t >> 6;
  const float* xb = x + n * 3 * NPIX;
  float a0 = 0.f, a1 = 0.f, a2 = 0.f, aq = 0.f;
  for (int p = t; p < NPIX; p += 256) {
    float v0 = xb[p], v1 = xb[NPIX + p], v2 = xb[2 * NPIX + p];
    a0 += v0; a1 += v1; a2 += v2;
    aq = fmaf(v0, v0, fmaf(v1, v1, fmaf(v2, v2, aq)));
  }
  #pragma unroll
  for (int m = 1; m < 64; m <<= 1) {
    a0 += __shfl_xor(a0, m, 64); a1 += __shfl_xor(a1, m, 64);
    a2 += __shfl_xor(a2, m, 64); aq += __shfl_xor(aq, m, 64);
  }
  if (lane == 0) { red[wv][0] = a0; red[wv][1] = a1; red[wv][2] = a2; red[wv][3] = aq; }
  __syncthreads();
  if (t == 0) {
    Sv[n*3+0] = red[0][0]+red[1][0]+red[2][0]+red[3][0];
    Sv[n*3+1] = red[0][1]+red[1][1]+red[2][1]+red[3][1];
    Sv[n*3+2] = red[0][2]+red[1][2]+red[2][2]+red[3][2];
    s2v[n]    = red[0][3]+red[1][3]+red[2][3]+red[3][3];
  }
}

// ---------- K2: main tile kernel -> per-tile partials (deterministic, no atomics) ----------
__global__ __launch_bounds__(256, 2)
void ncuts_main(const float* __restrict__ seg, const float* __restrict__ x,
                const float* __restrict__ Sv, const float* __restrict__ s2v,
                float* __restrict__ pA, float* __restrict__ pV) {
  __shared__ float sSeg[TW*TW*KK];   // [row][col][k], 54080 B, pixel stride 80B (16B aligned)
  __shared__ float sXi[3*TW*TW];     // [c][row][col], 8112 B
  __shared__ float sRed[4][2*KK];    // 640 B

  const int t = threadIdx.x;
  const int lane = t & 63, wv = t >> 6;
  const int tx = t & 15, ty = t >> 4;
  const int tcx = blockIdx.x, tcy = blockIdx.y, n = blockIdx.z;
  const int r0 = tcy * TILE - 5, c0 = tcx * TILE - 5;  // tile corner incl. halo

  // ---- stage xi tile (3*26*26 = 2028 elems) ----
  const float* xb = x + n * 3 * NPIX;
  for (int e = t; e < 3 * TW * TW; e += 256) {
    const int c = e / (TW * TW);
    const int rem = e - c * (TW * TW);
    const int rr = rem / TW;
    const int cc = rem - rr * TW;
    const int gr = r0 + rr, gc = c0 + cc;
    float v = 0.f;
    if ((unsigned)gr < XD && (unsigned)gc < YD) v = xb[c * NPIX + gr * YD + gc];
    sXi[e] = v;
  }

  // ---- stage seg tile (26*26*20 elems), lane mapping: 16 cols x 4 k per wave
  // LDS write banks: (20*cc + k) -> 2-way aliasing only (free)
  const float* sb = seg + n * KK * NPIX;
  for (int tt = wv; tt < 260; tt += 4) {   // 26 rows * 2 colgroups * 5 kgroups
    const int r = tt / 10;
    const int rem = tt - r * 10;
    const int cg = rem / 5;
    const int kg = (rem - cg * 5) << 2;
    const int cc = cg * 16 + (lane & 15);
    const int k  = kg + (lane >> 4);
    if (cc < TW) {
      const int gr = r0 + r, gc = c0 + cc;
      float v = 0.f;
      if ((unsigned)gr < XD && (unsigned)gc < YD) v = sb[k * NPIX + gr * YD + gc];
      sSeg[(r * TW + cc) * KK + k] = v;
    }
  }
  __syncthreads();

  // ---- per-thread center values ----
  const int xib = ty * TW + tx;            // corner-based xi index
  const float xc0 = sXi[xib + (5*TW+5)];
  const float xc1 = sXi[676 + xib + (5*TW+5)];
  const float xc2 = sXi[1352 + xib + (5*TW+5)];

  const float S0 = Sv[n*3+0], S1 = Sv[n*3+1], S2 = Sv[n*3+2], s2n = s2v[n];
  const float sqc = xc0*xc0 + xc1*xc1 + xc2*xc2;
  const float temp = 50176.f * sqc - 2.f * (xc0*S0 + xc1*S1 + xc2*S2) + s2n;

  float acc[KK];
  #pragma unroll
  for (int k = 0; k < KK; ++k) acc[k] = 0.f;

  const int segb = (ty * TW + tx) * KK;    // corner-based seg index (x20)

  // ---- main loop: 31 offsets, w computed once, 20 k's via 5x ds_read_b128 ----
  #pragma unroll
  for (int o = 0; o < NOFF; ++o) {
    const int rof = (DM[o] + 5) * TW + (DN[o] + 5);
    const float xs0 = sXi[xib + rof];
    const float xs1 = sXi[676 + xib + rof];
    const float xs2 = sXi[1352 + xib + rof];
    const float d0 = xc0 - xs0, d1 = xc1 - xs1, d2 = xc2 - xs2;
    const float cosc = (float)(DM[o]*DM[o] + DN[o]*DN[o]) * (1.0f / 40.0f);
    const float w = cosc * sqrtf(fmaf(d0, d0, fmaf(d1, d1, d2 * d2)));
    const float4* sp = reinterpret_cast<const float4*>(&sSeg[segb + rof * KK]);
    const float4 q0 = sp[0], q1 = sp[1], q2 = sp[2], q3 = sp[3], q4 = sp[4];
    acc[0]  = fmaf(w, q0.x, acc[0]);  acc[1]  = fmaf(w, q0.y, acc[1]);
    acc[2]  = fmaf(w, q0.z, acc[2]);  acc[3]  = fmaf(w, q0.w, acc[3]);
    acc[4]  = fmaf(w, q1.x, acc[4]);  acc[5]  = fmaf(w, q1.y, acc[5]);
    acc[6]  = fmaf(w, q1.z, acc[6]);  acc[7]  = fmaf(w, q1.w, acc[7]);
    acc[8]  = fmaf(w, q2.x, acc[8]);  acc[9]  = fmaf(w, q2.y, acc[9]);
    acc[10] = fmaf(w, q2.z, acc[10]); acc[11] = fmaf(w, q2.w, acc[11]);
    acc[12] = fmaf(w, q3.x, acc[12]); acc[13] = fmaf(w, q3.y, acc[13]);
    acc[14] = fmaf(w, q3.z, acc[14]); acc[15] = fmaf(w, q3.w, acc[15]);
    acc[16] = fmaf(w, q4.x, acc[16]); acc[17] = fmaf(w, q4.y, acc[17]);
    acc[18] = fmaf(w, q4.z, acc[18]); acc[19] = fmaf(w, q4.w, acc[19]);
  }

  // ---- center seg values ----
  float segc[KK];
  {
    const float4* cp = reinterpret_cast<const float4*>(&sSeg[segb + (5*TW+5) * KK]);
    const float4 q0 = cp[0], q1 = cp[1], q2 = cp[2], q3 = cp[3], q4 = cp[4];
    segc[0]=q0.x;  segc[1]=q0.y;  segc[2]=q0.z;  segc[3]=q0.w;
    segc[4]=q1.x;  segc[5]=q1.y;  segc[6]=q1.z;  segc[7]=q1.w;
    segc[8]=q2.x;  segc[9]=q2.y;  segc[10]=q2.z; segc[11]=q2.w;
    segc[12]=q3.x; segc[13]=q3.y; segc[14]=q3.z; segc[15]=q3.w;
    segc[16]=q4.x; segc[17]=q4.y; segc[18]=q4.z; segc[19]=q4.w;
  }

  // ---- packed 4-stream butterfly reduction: {pa,pv} x 2 k's per pass ----
  #pragma unroll
  for (int p = 0; p < KK / 2; ++p) {
    const int k0 = 2 * p, k1 = 2 * p + 1;
    float pa0 = segc[k0] * acc[k0], pv0 = segc[k0] * temp;
    float pa1 = segc[k1] * acc[k1], pv1 = segc[k1] * temp;
    float s0 = (lane & 1) ? pv0 : pa0;
    float g0 = (lane & 1) ? pa0 : pv0;
    s0 += __shfl_xor(g0, 1, 64);
    float s1 = (lane & 1) ? pv1 : pa1;
    float g1 = (lane & 1) ? pa1 : pv1;
    s1 += __shfl_xor(g1, 1, 64);
    float cv = (lane & 2) ? s1 : s0;
    float gv = (lane & 2) ? s0 : s1;
    cv += __shfl_xor(gv, 2, 64);
    cv += __shfl_xor(cv, 4, 64);
    cv += __shfl_xor(cv, 8, 64);
    cv += __shfl_xor(cv, 16, 64);
    cv += __shfl_xor(cv, 32, 64);
    // lane 0: pa_k0, lane 1: pv_k0, lane 2: pa_k1, lane 3: pv_k1
    if (lane < 4) sRed[wv][4 * p + lane] = cv;
  }
  __syncthreads();
  if (t < 2 * KK) {
    const float s = sRed[0][t] + sRed[1][t] + sRed[2][t] + sRed[3][t];
    const int tile = tcy * NT + tcx;
    const int k = t >> 1;
    float* dst = (t & 1) ? pV : pA;
    dst[tile * NKTOT + n * KK + k] = s;  // [tile][n*20+k], coalesced for K3
  }
}

// ---------- K3: reduce partials, form loss ----------
__global__ void ncuts_final(const float* __restrict__ pA, const float* __restrict__ pV,
                            float* __restrict__ out) {
  __shared__ float red[256];
  const int t = threadIdx.x;
  float r = 0.f;
  if (t < NKTOT) {
    float a = 0.f, v = 0.f;
    #pragma unroll 4
    for (int i = 0; i < NTILES; ++i) {
      a += pA[i * NKTOT + t];
      v += pV[i * NKTOT + t];
    }
    r = a / v;
  }
  red[t] = r;
  __syncthreads();
  for (int s = 128; s > 0; s >>= 1) {
    if (t < s) red[t] += red[t + s];
    __syncthreads();
  }
  if (t == 0) out[0] = (float)NKTOT - red[0];
}

extern "C" void kernel_launch(void* const* d_in, const int* in_sizes, int n_in,
                              void* d_out, int out_size, void* d_ws, size_t ws_size,
                              hipStream_t stream) {
  const float* seg = (const float*)d_in[0];
  const float* x   = (const float*)d_in[1];
  float* ws  = (float*)d_ws;
  float* pA  = ws;                       // 196*160 floats
  float* pV  = ws + NTILES * NKTOT;      // 196*160 floats
  float* Sv  = ws + 2 * NTILES * NKTOT;  // 24 floats
  float* s2v = Sv + 24;                  // 8 floats

  ncuts_stats<<<NB, 256, 0, stream>>>(x, Sv, s2v);
  dim3 grid(NT, NT, NB);
  ncuts_main<<<grid, 256, 0, stream>>>(seg, x, Sv, s2v, pA, pV);
  ncuts_final<<<1, 256, 0, stream>>>(pA, pV, (float*)d_out);
}

// Round 3
// 289.828 us; speedup vs baseline: 2.1799x; 2.1799x over previous
//
#include <hip/hip_runtime.h>

#define NB 8
#define KK 20
#define XD 224
#define YD 224
#define NPIX (XD*YD)        // 50176
#define TILE 16
#define NT 14               // 224/16
#define TW 26               // TILE + 2*5 halo
#define NOFF 31
#define NKTOT (NB*KK)       // 160
#define NTILES (NT*NT)      // 196

namespace {
// offsets with sqrt(dm^2+dn^2) >= 5, dm,dn in [-5,4] (faithful to source)
constexpr int DM[NOFF] = {
  -5,-5,-5,-5,-5,-5,-5,-5,-5,-5,
  -4,-4,-4,-4,-4,
  -3,-3,-3,
  -2,-1, 0, 1, 2,
   3, 3, 3,
   4, 4, 4, 4, 4};
constexpr int DN[NOFF] = {
  -5,-4,-3,-2,-1, 0, 1, 2, 3, 4,
  -5,-4,-3, 3, 4,
  -5,-4, 4,
  -5,-5,-5,-5,-5,
  -5,-4, 4,
  -5,-4,-3, 3, 4};

// Precomputed per-offset constants (uniform scalar loads in the loop):
// ROFXI  = (dm+5)*TW + (dn+5)         : xi-tile relative index
// ROFSEG = ROFXI * KK                 : seg-tile relative index (float units)
// COSC   = (dm^2+dn^2)/40             : dist^2 / sigma_x weight
constexpr int ROFXI[NOFF] = {
  (DM[0]+5)*TW+(DN[0]+5),  (DM[1]+5)*TW+(DN[1]+5),  (DM[2]+5)*TW+(DN[2]+5),
  (DM[3]+5)*TW+(DN[3]+5),  (DM[4]+5)*TW+(DN[4]+5),  (DM[5]+5)*TW+(DN[5]+5),
  (DM[6]+5)*TW+(DN[6]+5),  (DM[7]+5)*TW+(DN[7]+5),  (DM[8]+5)*TW+(DN[8]+5),
  (DM[9]+5)*TW+(DN[9]+5),  (DM[10]+5)*TW+(DN[10]+5),(DM[11]+5)*TW+(DN[11]+5),
  (DM[12]+5)*TW+(DN[12]+5),(DM[13]+5)*TW+(DN[13]+5),(DM[14]+5)*TW+(DN[14]+5),
  (DM[15]+5)*TW+(DN[15]+5),(DM[16]+5)*TW+(DN[16]+5),(DM[17]+5)*TW+(DN[17]+5),
  (DM[18]+5)*TW+(DN[18]+5),(DM[19]+5)*TW+(DN[19]+5),(DM[20]+5)*TW+(DN[20]+5),
  (DM[21]+5)*TW+(DN[21]+5),(DM[22]+5)*TW+(DN[22]+5),(DM[23]+5)*TW+(DN[23]+5),
  (DM[24]+5)*TW+(DN[24]+5),(DM[25]+5)*TW+(DN[25]+5),(DM[26]+5)*TW+(DN[26]+5),
  (DM[27]+5)*TW+(DN[27]+5),(DM[28]+5)*TW+(DN[28]+5),(DM[29]+5)*TW+(DN[29]+5),
  (DM[30]+5)*TW+(DN[30]+5)};
constexpr int ROFSEG[NOFF] = {
  ROFXI[0]*KK,  ROFXI[1]*KK,  ROFXI[2]*KK,  ROFXI[3]*KK,  ROFXI[4]*KK,
  ROFXI[5]*KK,  ROFXI[6]*KK,  ROFXI[7]*KK,  ROFXI[8]*KK,  ROFXI[9]*KK,
  ROFXI[10]*KK, ROFXI[11]*KK, ROFXI[12]*KK, ROFXI[13]*KK, ROFXI[14]*KK,
  ROFXI[15]*KK, ROFXI[16]*KK, ROFXI[17]*KK, ROFXI[18]*KK, ROFXI[19]*KK,
  ROFXI[20]*KK, ROFXI[21]*KK, ROFXI[22]*KK, ROFXI[23]*KK, ROFXI[24]*KK,
  ROFXI[25]*KK, ROFXI[26]*KK, ROFXI[27]*KK, ROFXI[28]*KK, ROFXI[29]*KK,
  ROFXI[30]*KK};
constexpr float COSC[NOFF] = {
  (DM[0]*DM[0]+DN[0]*DN[0])/40.0f,   (DM[1]*DM[1]+DN[1]*DN[1])/40.0f,
  (DM[2]*DM[2]+DN[2]*DN[2])/40.0f,   (DM[3]*DM[3]+DN[3]*DN[3])/40.0f,
  (DM[4]*DM[4]+DN[4]*DN[4])/40.0f,   (DM[5]*DM[5]+DN[5]*DN[5])/40.0f,
  (DM[6]*DM[6]+DN[6]*DN[6])/40.0f,   (DM[7]*DM[7]+DN[7]*DN[7])/40.0f,
  (DM[8]*DM[8]+DN[8]*DN[8])/40.0f,   (DM[9]*DM[9]+DN[9]*DN[9])/40.0f,
  (DM[10]*DM[10]+DN[10]*DN[10])/40.0f,(DM[11]*DM[11]+DN[11]*DN[11])/40.0f,
  (DM[12]*DM[12]+DN[12]*DN[12])/40.0f,(DM[13]*DM[13]+DN[13]*DN[13])/40.0f,
  (DM[14]*DM[14]+DN[14]*DN[14])/40.0f,(DM[15]*DM[15]+DN[15]*DN[15])/40.0f,
  (DM[16]*DM[16]+DN[16]*DN[16])/40.0f,(DM[17]*DM[17]+DN[17]*DN[17])/40.0f,
  (DM[18]*DM[18]+DN[18]*DN[18])/40.0f,(DM[19]*DM[19]+DN[19]*DN[19])/40.0f,
  (DM[20]*DM[20]+DN[20]*DN[20])/40.0f,(DM[21]*DM[21]+DN[21]*DN[21])/40.0f,
  (DM[22]*DM[22]+DN[22]*DN[22])/40.0f,(DM[23]*DM[23]+DN[23]*DN[23])/40.0f,
  (DM[24]*DM[24]+DN[24]*DN[24])/40.0f,(DM[25]*DM[25]+DN[25]*DN[25])/40.0f,
  (DM[26]*DM[26]+DN[26]*DN[26])/40.0f,(DM[27]*DM[27]+DN[27]*DN[27])/40.0f,
  (DM[28]*DM[28]+DN[28]*DN[28])/40.0f,(DM[29]*DM[29]+DN[29]*DN[29])/40.0f,
  (DM[30]*DM[30]+DN[30]*DN[30])/40.0f};
}

// ---------- K1: per-batch x sums: S[n][3], s2[n] ----------
__global__ void ncuts_stats(const float* __restrict__ x,
                            float* __restrict__ Sv, float* __restrict__ s2v) {
  __shared__ float red[4][4];
  const int n = blockIdx.x, t = threadIdx.x;
  const int lane = t & 63, wv = t >> 6;
  const float* xb = x + n * 3 * NPIX;
  float a0 = 0.f, a1 = 0.f, a2 = 0.f, aq = 0.f;
  for (int p = t; p < NPIX; p += 256) {
    float v0 = xb[p], v1 = xb[NPIX + p], v2 = xb[2 * NPIX + p];
    a0 += v0; a1 += v1; a2 += v2;
    aq = fmaf(v0, v0, fmaf(v1, v1, fmaf(v2, v2, aq)));
  }
  #pragma unroll
  for (int m = 1; m < 64; m <<= 1) {
    a0 += __shfl_xor(a0, m, 64); a1 += __shfl_xor(a1, m, 64);
    a2 += __shfl_xor(a2, m, 64); aq += __shfl_xor(aq, m, 64);
  }
  if (lane == 0) { red[wv][0] = a0; red[wv][1] = a1; red[wv][2] = a2; red[wv][3] = aq; }
  __syncthreads();
  if (t == 0) {
    Sv[n*3+0] = red[0][0]+red[1][0]+red[2][0]+red[3][0];
    Sv[n*3+1] = red[0][1]+red[1][1]+red[2][1]+red[3][1];
    Sv[n*3+2] = red[0][2]+red[1][2]+red[2][2]+red[3][2];
    s2v[n]    = red[0][3]+red[1][3]+red[2][3]+red[3][3];
  }
}

// ---------- K2: main tile kernel -> per-tile partials (deterministic, no atomics) ----------
__global__ __launch_bounds__(256, 2)
void ncuts_main(const float* __restrict__ seg, const float* __restrict__ x,
                const float* __restrict__ Sv, const float* __restrict__ s2v,
                float* __restrict__ pA, float* __restrict__ pV) {
  __shared__ float sSeg[TW*TW*KK];   // [row][col][k], 54080 B, pixel stride 80B (16B aligned)
  __shared__ float sXi[3*TW*TW];     // [c][row][col], 8112 B
  __shared__ float sRed[4][2*KK];    // 640 B

  const int t = threadIdx.x;
  const int lane = t & 63, wv = t >> 6;
  const int tx = t & 15, ty = t >> 4;
  const int tcx = blockIdx.x, tcy = blockIdx.y, n = blockIdx.z;
  const int r0 = tcy * TILE - 5, c0 = tcx * TILE - 5;  // tile corner incl. halo

  // ---- stage xi tile (3*26*26 = 2028 elems) ----
  const float* xb = x + n * 3 * NPIX;
  for (int e = t; e < 3 * TW * TW; e += 256) {
    const int c = e / (TW * TW);
    const int rem = e - c * (TW * TW);
    const int rr = rem / TW;
    const int cc = rem - rr * TW;
    const int gr = r0 + rr, gc = c0 + cc;
    float v = 0.f;
    if ((unsigned)gr < XD && (unsigned)gc < YD) v = xb[c * NPIX + gr * YD + gc];
    sXi[e] = v;
  }

  // ---- stage seg tile (26*26*20 elems), lane mapping: 16 cols x 4 k per wave
  // LDS write banks: (20*cc + k) -> 2-way aliasing only (free)
  const float* sb = seg + n * KK * NPIX;
  for (int tt = wv; tt < 260; tt += 4) {   // 26 rows * 2 colgroups * 5 kgroups
    const int r = tt / 10;
    const int rem = tt - r * 10;
    const int cg = rem / 5;
    const int kg = (rem - cg * 5) << 2;
    const int cc = cg * 16 + (lane & 15);
    const int k  = kg + (lane >> 4);
    if (cc < TW) {
      const int gr = r0 + r, gc = c0 + cc;
      float v = 0.f;
      if ((unsigned)gr < XD && (unsigned)gc < YD) v = sb[k * NPIX + gr * YD + gc];
      sSeg[(r * TW + cc) * KK + k] = v;
    }
  }
  __syncthreads();

  // ---- per-thread center values ----
  const int xib = ty * TW + tx;            // corner-based xi index
  const float xc0 = sXi[xib + (5*TW+5)];
  const float xc1 = sXi[676 + xib + (5*TW+5)];
  const float xc2 = sXi[1352 + xib + (5*TW+5)];

  const float S0 = Sv[n*3+0], S1 = Sv[n*3+1], S2 = Sv[n*3+2], s2n = s2v[n];
  const float sqc = xc0*xc0 + xc1*xc1 + xc2*xc2;
  const float temp = 50176.f * sqc - 2.f * (xc0*S0 + xc1*S1 + xc2*S2) + s2n;

  float acc[KK];
  #pragma unroll
  for (int k = 0; k < KK; ++k) acc[k] = 0.f;

  const int segb = (ty * TW + tx) * KK;    // corner-based seg index (x20)

  // ---- main loop: 31 offsets, w computed once, 20 k's via 5x ds_read_b128 ----
  // unroll 2 (NOT full): full unroll caused pre-RA load hoisting -> ~600MB/dir
  // scratch spill traffic (R1: WRITE_SIZE=646MB vs 0.25MB of real writes).
  #pragma unroll 2
  for (int o = 0; o < NOFF; ++o) {
    const int rof = ROFXI[o];
    const float xs0 = sXi[xib + rof];
    const float xs1 = sXi[676 + xib + rof];
    const float xs2 = sXi[1352 + xib + rof];
    const float d0 = xc0 - xs0, d1 = xc1 - xs1, d2 = xc2 - xs2;
    const float w = COSC[o] * sqrtf(fmaf(d0, d0, fmaf(d1, d1, d2 * d2)));
    const float4* sp = reinterpret_cast<const float4*>(&sSeg[segb + ROFSEG[o]]);
    const float4 q0 = sp[0], q1 = sp[1], q2 = sp[2], q3 = sp[3], q4 = sp[4];
    acc[0]  = fmaf(w, q0.x, acc[0]);  acc[1]  = fmaf(w, q0.y, acc[1]);
    acc[2]  = fmaf(w, q0.z, acc[2]);  acc[3]  = fmaf(w, q0.w, acc[3]);
    acc[4]  = fmaf(w, q1.x, acc[4]);  acc[5]  = fmaf(w, q1.y, acc[5]);
    acc[6]  = fmaf(w, q1.z, acc[6]);  acc[7]  = fmaf(w, q1.w, acc[7]);
    acc[8]  = fmaf(w, q2.x, acc[8]);  acc[9]  = fmaf(w, q2.y, acc[9]);
    acc[10] = fmaf(w, q2.z, acc[10]); acc[11] = fmaf(w, q2.w, acc[11]);
    acc[12] = fmaf(w, q3.x, acc[12]); acc[13] = fmaf(w, q3.y, acc[13]);
    acc[14] = fmaf(w, q3.z, acc[14]); acc[15] = fmaf(w, q3.w, acc[15]);
    acc[16] = fmaf(w, q4.x, acc[16]); acc[17] = fmaf(w, q4.y, acc[17]);
    acc[18] = fmaf(w, q4.z, acc[18]); acc[19] = fmaf(w, q4.w, acc[19]);
  }

  // ---- center seg values ----
  float segc[KK];
  {
    const float4* cp = reinterpret_cast<const float4*>(&sSeg[segb + (5*TW+5) * KK]);
    const float4 q0 = cp[0], q1 = cp[1], q2 = cp[2], q3 = cp[3], q4 = cp[4];
    segc[0]=q0.x;  segc[1]=q0.y;  segc[2]=q0.z;  segc[3]=q0.w;
    segc[4]=q1.x;  segc[5]=q1.y;  segc[6]=q1.z;  segc[7]=q1.w;
    segc[8]=q2.x;  segc[9]=q2.y;  segc[10]=q2.z; segc[11]=q2.w;
    segc[12]=q3.x; segc[13]=q3.y; segc[14]=q3.z; segc[15]=q3.w;
    segc[16]=q4.x; segc[17]=q4.y; segc[18]=q4.z; segc[19]=q4.w;
  }

  // ---- packed 4-stream butterfly reduction: {pa,pv} x 2 k's per pass ----
  #pragma unroll
  for (int p = 0; p < KK / 2; ++p) {
    const int k0 = 2 * p, k1 = 2 * p + 1;
    float pa0 = segc[k0] * acc[k0], pv0 = segc[k0] * temp;
    float pa1 = segc[k1] * acc[k1], pv1 = segc[k1] * temp;
    float s0 = (lane & 1) ? pv0 : pa0;
    float g0 = (lane & 1) ? pa0 : pv0;
    s0 += __shfl_xor(g0, 1, 64);
    float s1 = (lane & 1) ? pv1 : pa1;
    float g1 = (lane & 1) ? pa1 : pv1;
    s1 += __shfl_xor(g1, 1, 64);
    float cv = (lane & 2) ? s1 : s0;
    float gv = (lane & 2) ? s0 : s1;
    cv += __shfl_xor(gv, 2, 64);
    cv += __shfl_xor(cv, 4, 64);
    cv += __shfl_xor(cv, 8, 64);
    cv += __shfl_xor(cv, 16, 64);
    cv += __shfl_xor(cv, 32, 64);
    // lane 0: pa_k0, lane 1: pv_k0, lane 2: pa_k1, lane 3: pv_k1
    if (lane < 4) sRed[wv][4 * p + lane] = cv;
  }
  __syncthreads();
  if (t < 2 * KK) {
    const float s = sRed[0][t] + sRed[1][t] + sRed[2][t] + sRed[3][t];
    const int tile = tcy * NT + tcx;
    const int k = t >> 1;
    float* dst = (t & 1) ? pV : pA;
    dst[tile * NKTOT + n * KK + k] = s;  // [tile][n*20+k], coalesced for K3
  }
}

// ---------- K3: reduce partials, form loss ----------
__global__ void ncuts_final(const float* __restrict__ pA, const float* __restrict__ pV,
                            float* __restrict__ out) {
  __shared__ float red[256];
  const int t = threadIdx.x;
  float r = 0.f;
  if (t < NKTOT) {
    float a = 0.f, v = 0.f;
    #pragma unroll 4
    for (int i = 0; i < NTILES; ++i) {
      a += pA[i * NKTOT + t];
      v += pV[i * NKTOT + t];
    }
    r = a / v;
  }
  red[t] = r;
  __syncthreads();
  for (int s = 128; s > 0; s >>= 1) {
    if (t < s) red[t] += red[t + s];
    __syncthreads();
  }
  if (t == 0) out[0] = (float)NKTOT - red[0];
}

extern "C" void kernel_launch(void* const* d_in, const int* in_sizes, int n_in,
                              void* d_out, int out_size, void* d_ws, size_t ws_size,
                              hipStream_t stream) {
  const float* seg = (const float*)d_in[0];
  const float* x   = (const float*)d_in[1];
  float* ws  = (float*)d_ws;
  float* pA  = ws;                       // 196*160 floats
  float* pV  = ws + NTILES * NKTOT;      // 196*160 floats
  float* Sv  = ws + 2 * NTILES * NKTOT;  // 24 floats
  float* s2v = Sv + 24;                  // 8 floats

  ncuts_stats<<<NB, 256, 0, stream>>>(x, Sv, s2v);
  dim3 grid(NT, NT, NB);
  ncuts_main<<<grid, 256, 0, stream>>>(seg, x, Sv, s2v, pA, pV);
  ncuts_final<<<1, 256, 0, stream>>>(pA, pV, (float*)d_out);
}

// Round 5
// 174.251 us; speedup vs baseline: 3.6257x; 1.6633x over previous
//
#include <hip/hip_runtime.h>

#define NB 8
#define KK 20
#define XD 224
#define YD 224
#define NPIX (XD*YD)        // 50176
#define TILE 16
#define NT 14               // 224/16
#define TW 26               // TILE + 2*5 halo
#define NOFF 31
#define NKTOT (NB*KK)       // 160
#define NTILES (NT*NT)      // 196
#define NPH 3               // k-phases
#define KPH 7               // k per phase (last phase has 6)
#define KS 8                // LDS k-slots per pixel (zero-padded)
#define SB 32               // stats slices per batch

namespace {
// offsets with sqrt(dm^2+dn^2) >= 5, dm,dn in [-5,4] (faithful to source)
constexpr int DM[NOFF] = {
  -5,-5,-5,-5,-5,-5,-5,-5,-5,-5,
  -4,-4,-4,-4,-4,
  -3,-3,-3,
  -2,-1, 0, 1, 2,
   3, 3, 3,
   4, 4, 4, 4, 4};
constexpr int DN[NOFF] = {
  -5,-4,-3,-2,-1, 0, 1, 2, 3, 4,
  -5,-4,-3, 3, 4,
  -5,-4, 4,
  -5,-5,-5,-5,-5,
  -5,-4, 4,
  -5,-4,-3, 3, 4};

constexpr int ROFXI[NOFF] = {
  (DM[0]+5)*TW+(DN[0]+5),  (DM[1]+5)*TW+(DN[1]+5),  (DM[2]+5)*TW+(DN[2]+5),
  (DM[3]+5)*TW+(DN[3]+5),  (DM[4]+5)*TW+(DN[4]+5),  (DM[5]+5)*TW+(DN[5]+5),
  (DM[6]+5)*TW+(DN[6]+5),  (DM[7]+5)*TW+(DN[7]+5),  (DM[8]+5)*TW+(DN[8]+5),
  (DM[9]+5)*TW+(DN[9]+5),  (DM[10]+5)*TW+(DN[10]+5),(DM[11]+5)*TW+(DN[11]+5),
  (DM[12]+5)*TW+(DN[12]+5),(DM[13]+5)*TW+(DN[13]+5),(DM[14]+5)*TW+(DN[14]+5),
  (DM[15]+5)*TW+(DN[15]+5),(DM[16]+5)*TW+(DN[16]+5),(DM[17]+5)*TW+(DN[17]+5),
  (DM[18]+5)*TW+(DN[18]+5),(DM[19]+5)*TW+(DN[19]+5),(DM[20]+5)*TW+(DN[20]+5),
  (DM[21]+5)*TW+(DN[21]+5),(DM[22]+5)*TW+(DN[22]+5),(DM[23]+5)*TW+(DN[23]+5),
  (DM[24]+5)*TW+(DN[24]+5),(DM[25]+5)*TW+(DN[25]+5),(DM[26]+5)*TW+(DN[26]+5),
  (DM[27]+5)*TW+(DN[27]+5),(DM[28]+5)*TW+(DN[28]+5),(DM[29]+5)*TW+(DN[29]+5),
  (DM[30]+5)*TW+(DN[30]+5)};
constexpr float COSC[NOFF] = {
  (DM[0]*DM[0]+DN[0]*DN[0])/40.0f,   (DM[1]*DM[1]+DN[1]*DN[1])/40.0f,
  (DM[2]*DM[2]+DN[2]*DN[2])/40.0f,   (DM[3]*DM[3]+DN[3]*DN[3])/40.0f,
  (DM[4]*DM[4]+DN[4]*DN[4])/40.0f,   (DM[5]*DM[5]+DN[5]*DN[5])/40.0f,
  (DM[6]*DM[6]+DN[6]*DN[6])/40.0f,   (DM[7]*DM[7]+DN[7]*DN[7])/40.0f,
  (DM[8]*DM[8]+DN[8]*DN[8])/40.0f,   (DM[9]*DM[9]+DN[9]*DN[9])/40.0f,
  (DM[10]*DM[10]+DN[10]*DN[10])/40.0f,(DM[11]*DM[11]+DN[11]*DN[11])/40.0f,
  (DM[12]*DM[12]+DN[12]*DN[12])/40.0f,(DM[13]*DM[13]+DN[13]*DN[13])/40.0f,
  (DM[14]*DM[14]+DN[14]*DN[14])/40.0f,(DM[15]*DM[15]+DN[15]*DN[15])/40.0f,
  (DM[16]*DM[16]+DN[16]*DN[16])/40.0f,(DM[17]*DM[17]+DN[17]*DN[17])/40.0f,
  (DM[18]*DM[18]+DN[18]*DN[18])/40.0f,(DM[19]*DM[19]+DN[19]*DN[19])/40.0f,
  (DM[20]*DM[20]+DN[20]*DN[20])/40.0f,(DM[21]*DM[21]+DN[21]*DN[21])/40.0f,
  (DM[22]*DM[22]+DN[22]*DN[22])/40.0f,(DM[23]*DM[23]+DN[23]*DN[23])/40.0f,
  (DM[24]*DM[24]+DN[24]*DN[24])/40.0f,(DM[25]*DM[25]+DN[25]*DN[25])/40.0f,
  (DM[26]*DM[26]+DN[26]*DN[26])/40.0f,(DM[27]*DM[27]+DN[27]*DN[27])/40.0f,
  (DM[28]*DM[28]+DN[28]*DN[28])/40.0f,(DM[29]*DM[29]+DN[29]*DN[29])/40.0f,
  (DM[30]*DM[30]+DN[30]*DN[30])/40.0f};
}

// ---------- K1a: per-(batch,slice) partial sums over x ----------
__global__ void ncuts_stats1(const float* __restrict__ x, float* __restrict__ part) {
  __shared__ float red[4][4];
  const int b = blockIdx.x;
  const int n = b >> 5, s = b & 31;          // SB = 32
  const int t = threadIdx.x;
  const int lane = t & 63, wv = t >> 6;
  const float* xb = x + n * 3 * NPIX;
  const int base = s * (NPIX / SB);          // 1568 per slice
  float a0 = 0.f, a1 = 0.f, a2 = 0.f, aq = 0.f;
  for (int i = t; i < NPIX / SB; i += 256) {
    const int p = base + i;
    float v0 = xb[p], v1 = xb[NPIX + p], v2 = xb[2 * NPIX + p];
    a0 += v0; a1 += v1; a2 += v2;
    aq = fmaf(v0, v0, fmaf(v1, v1, fmaf(v2, v2, aq)));
  }
  #pragma unroll
  for (int m = 1; m < 64; m <<= 1) {
    a0 += __shfl_xor(a0, m, 64); a1 += __shfl_xor(a1, m, 64);
    a2 += __shfl_xor(a2, m, 64); aq += __shfl_xor(aq, m, 64);
  }
  if (lane == 0) { red[wv][0] = a0; red[wv][1] = a1; red[wv][2] = a2; red[wv][3] = aq; }
  __syncthreads();
  if (t < 4) part[b * 4 + t] = red[0][t] + red[1][t] + red[2][t] + red[3][t];
}

// ---------- K1b: reduce slice partials -> S[n][3], s2[n] ----------
__global__ void ncuts_stats2(const float* __restrict__ part,
                             float* __restrict__ Sv, float* __restrict__ s2v) {
  const int t = threadIdx.x;
  if (t < NB * 4) {
    const int n = t >> 2, val = t & 3;
    float s = 0.f;
    #pragma unroll 4
    for (int i = 0; i < SB; ++i) s += part[(n * SB + i) * 4 + val];
    if (val < 3) Sv[n * 3 + val] = s; else s2v[n] = s;
  }
}

// ---------- K2: main tile kernel, 3 k-phases sharing one LDS seg buffer ----------
// LDS 33.2KB -> 4 blocks/CU (16 waves/CU) vs R3's 62.9KB/2 blocks (latency-bound, occ 18.8%).
__global__ __launch_bounds__(256, 4)
void ncuts_main(const float* __restrict__ seg, const float* __restrict__ x,
                const float* __restrict__ Sv, const float* __restrict__ s2v,
                float* __restrict__ pA, float* __restrict__ pV) {
  __shared__ __align__(16) float sSeg[TW*TW*KS];   // [pix][kslot], 21632 B, 32B/pixel
  __shared__ __align__(16) float sXi[TW*TW*4];     // [pix][{x0,x1,x2,0}], 10816 B
  __shared__ float sRed[4][48];                    // 768 B (slots >=40 are pad-k spill)

  const int t = threadIdx.x;
  const int lane = t & 63, wv = t >> 6;
  const int tx = t & 15, ty = t >> 4;
  const int tcx = blockIdx.x, tcy = blockIdx.y, n = blockIdx.z;
  const int r0 = tcy * TILE - 5, c0 = tcx * TILE - 5;

  // ---- stage xi packed float4 (676 pixels) ----
  const float* xb = x + n * 3 * NPIX;
  for (int e = t; e < TW * TW; e += 256) {
    const int rr = e / TW, cc = e - rr * TW;
    const int gr = r0 + rr, gc = c0 + cc;
    float v0 = 0.f, v1 = 0.f, v2 = 0.f;
    if ((unsigned)gr < XD && (unsigned)gc < YD) {
      const int g = gr * YD + gc;
      v0 = xb[g]; v1 = xb[NPIX + g]; v2 = xb[2 * NPIX + g];
    }
    *reinterpret_cast<float4*>(&sXi[e * 4]) = make_float4(v0, v1, v2, 0.f);
  }

  const int xib = ty * TW + tx;                  // corner-based pixel index
  const int cen = xib + (5 * TW + 5);

  const float S0 = Sv[n*3+0], S1 = Sv[n*3+1], S2 = Sv[n*3+2], s2n = s2v[n];
  const float* sb = seg + n * KK * NPIX;

  float xc0, xc1, xc2, temp;
  bool haveCenter = false;

  #pragma unroll 1
  for (int p = 0; p < NPH; ++p) {
    const int kbase = p * KPH;
    const int kcnt  = (p == NPH - 1) ? (KK - 2 * KPH) : KPH;   // 7,7,6

    __syncthreads();   // prior phase's sSeg reads done (p=0: xi staging ordered too)

    // stage this phase's seg slots: e = ks*676 + pix (coalesced global reads)
    for (int e = t; e < TW * TW * KS; e += 256) {
      const int ks = e / (TW * TW);
      const int pix = e - ks * (TW * TW);
      const int rr = pix / TW, cc = pix - rr * TW;
      const int gr = r0 + rr, gc = c0 + cc;
      float v = 0.f;
      if (ks < kcnt && (unsigned)gr < XD && (unsigned)gc < YD)
        v = sb[(kbase + ks) * NPIX + gr * YD + gc];
      sSeg[pix * KS + ks] = v;
    }
    __syncthreads();

    if (!haveCenter) {
      const float4 xc = *reinterpret_cast<const float4*>(&sXi[cen * 4]);
      xc0 = xc.x; xc1 = xc.y; xc2 = xc.z;
      const float sqc = xc0*xc0 + xc1*xc1 + xc2*xc2;
      temp = 50176.f * sqc - 2.f * (xc0*S0 + xc1*S1 + xc2*S2) + s2n;
      haveCenter = true;
    }

    float acc[KS];
    #pragma unroll
    for (int k = 0; k < KS; ++k) acc[k] = 0.f;

    // unroll 2 (NOT full): full unroll spilled to scratch in R1 (646MB write traffic)
    #pragma unroll 2
    for (int o = 0; o < NOFF; ++o) {
      const int rof = ROFXI[o];
      const float4 xs = *reinterpret_cast<const float4*>(&sXi[(xib + rof) * 4]);
      const float d0 = xc0 - xs.x, d1 = xc1 - xs.y, d2 = xc2 - xs.z;
      const float w = COSC[o] * sqrtf(fmaf(d0, d0, fmaf(d1, d1, d2 * d2)));
      const float4* sp = reinterpret_cast<const float4*>(&sSeg[(xib + rof) * KS]);
      const float4 q0 = sp[0], q1 = sp[1];
      acc[0] = fmaf(w, q0.x, acc[0]); acc[1] = fmaf(w, q0.y, acc[1]);
      acc[2] = fmaf(w, q0.z, acc[2]); acc[3] = fmaf(w, q0.w, acc[3]);
      acc[4] = fmaf(w, q1.x, acc[4]); acc[5] = fmaf(w, q1.y, acc[5]);
      acc[6] = fmaf(w, q1.z, acc[6]); acc[7] = fmaf(w, q1.w, acc[7]);
    }

    // center seg for this phase's k's (pad slots are 0 -> pa/pv contributions 0)
    const float4* cp = reinterpret_cast<const float4*>(&sSeg[cen * KS]);
    const float4 c0v = cp[0], c1v = cp[1];
    const float segc[KS] = {c0v.x, c0v.y, c0v.z, c0v.w, c1v.x, c1v.y, c1v.z, c1v.w};

    // packed butterfly: {pa,pv} x 2 kslots per pass; write at global-k slots.
    // Pad-k writes (segc=0 -> value 0) land on slots later overwritten by the
    // owning phase (same-thread program order) or on slots >= 40 (ignored).
    #pragma unroll
    for (int pp = 0; pp < KS / 2; ++pp) {
      const int s0i = 2 * pp, s1i = 2 * pp + 1;
      float pa0 = segc[s0i] * acc[s0i], pv0 = segc[s0i] * temp;
      float pa1 = segc[s1i] * acc[s1i], pv1 = segc[s1i] * temp;
      float s0 = (lane & 1) ? pv0 : pa0;
      float g0 = (lane & 1) ? pa0 : pv0;
      s0 += __shfl_xor(g0, 1, 64);
      float s1 = (lane & 1) ? pv1 : pa1;
      float g1 = (lane & 1) ? pa1 : pv1;
      s1 += __shfl_xor(g1, 1, 64);
      float cv = (lane & 2) ? s1 : s0;
      float gv = (lane & 2) ? s0 : s1;
      cv += __shfl_xor(gv, 2, 64);
      cv += __shfl_xor(cv, 4, 64);
      cv += __shfl_xor(cv, 8, 64);
      cv += __shfl_xor(cv, 16, 64);
      cv += __shfl_xor(cv, 32, 64);
      // lane 0: pa(k0g), lane 1: pv(k0g), lane 2: pa(k0g+1), lane 3: pv(k0g+1)
      const int k0g = kbase + 2 * pp;
      if (lane < 4) sRed[wv][2 * k0g + lane] = cv;
    }
  }

  __syncthreads();
  if (t < 2 * KK) {
    const float s = sRed[0][t] + sRed[1][t] + sRed[2][t] + sRed[3][t];
    const int tile = tcy * NT + tcx;
    const int k = t >> 1;
    float* dst = (t & 1) ? pV : pA;
    dst[tile * NKTOT + n * KK + k] = s;  // [tile][n*20+k], coalesced for K3
  }
}

// ---------- K3: reduce partials, form loss (1024 thr, 4 tile-groups) ----------
__global__ void ncuts_final(const float* __restrict__ pA, const float* __restrict__ pV,
                            float* __restrict__ out) {
  __shared__ float rA[4][NKTOT];
  __shared__ float rV[4][NKTOT];
  __shared__ float red[256];
  const int t = threadIdx.x;
  const int grp = t >> 8, i = t & 255;
  if (i < NKTOT) {
    float a = 0.f, v = 0.f;
    #pragma unroll 7
    for (int j = 0; j < NTILES / 4; ++j) {       // 49 tiles per group
      const int tile = grp * (NTILES / 4) + j;
      a += pA[tile * NKTOT + i];
      v += pV[tile * NKTOT + i];
    }
    rA[grp][i] = a; rV[grp][i] = v;
  }
  __syncthreads();
  if (t < 256) {
    float r = 0.f;
    if (t < NKTOT) {
      const float a = rA[0][t] + rA[1][t] + rA[2][t] + rA[3][t];
      const float v = rV[0][t] + rV[1][t] + rV[2][t] + rV[3][t];
      r = a / v;
    }
    red[t] = r;
  }
  __syncthreads();
  for (int s = 128; s > 0; s >>= 1) {
    if (t < s) red[t] += red[t + s];
    __syncthreads();
  }
  if (t == 0) out[0] = (float)NKTOT - red[0];
}

extern "C" void kernel_launch(void* const* d_in, const int* in_sizes, int n_in,
                              void* d_out, int out_size, void* d_ws, size_t ws_size,
                              hipStream_t stream) {
  const float* seg = (const float*)d_in[0];
  const float* x   = (const float*)d_in[1];
  float* ws   = (float*)d_ws;
  float* pA   = ws;                        // 31360 floats
  float* pV   = ws + NTILES * NKTOT;       // 31360 floats
  float* Sv   = ws + 2 * NTILES * NKTOT;   // 24
  float* s2v  = Sv + 24;                   // 8
  float* part = s2v + 8;                   // NB*SB*4 = 1024

  ncuts_stats1<<<NB * SB, 256, 0, stream>>>(x, part);
  ncuts_stats2<<<1, 64, 0, stream>>>(part, Sv, s2v);
  dim3 grid(NT, NT, NB);
  ncuts_main<<<grid, 256, 0, stream>>>(seg, x, Sv, s2v, pA, pV);
  ncuts_final<<<1, 1024, 0, stream>>>(pA, pV, (float*)d_out);
}

// Round 6
// 148.446 us; speedup vs baseline: 4.2560x; 1.1738x over previous
//
#include <hip/hip_runtime.h>

#define NB 8
#define KK 20
#define XD 224
#define YD 224
#define NPIX (XD*YD)        // 50176
#define TILE 16
#define NT 14               // 224/16
#define TW 26               // TILE + 2*5 halo
#define NOFF 31
#define NKTOT (NB*KK)       // 160
#define NTILES (NT*NT)      // 196
#define NPH 3               // k-phases
#define KPH 7               // k per phase (last phase has 6)
#define SB 32               // stats slices per batch

namespace {
// offsets with sqrt(dm^2+dn^2) >= 5, dm,dn in [-5,4] (faithful to source)
constexpr int DM[NOFF] = {
  -5,-5,-5,-5,-5,-5,-5,-5,-5,-5,
  -4,-4,-4,-4,-4,
  -3,-3,-3,
  -2,-1, 0, 1, 2,
   3, 3, 3,
   4, 4, 4, 4, 4};
constexpr int DN[NOFF] = {
  -5,-4,-3,-2,-1, 0, 1, 2, 3, 4,
  -5,-4,-3, 3, 4,
  -5,-4, 4,
  -5,-5,-5,-5,-5,
  -5,-4, 4,
  -5,-4,-3, 3, 4};

constexpr int ROFXI[NOFF] = {
  (DM[0]+5)*TW+(DN[0]+5),  (DM[1]+5)*TW+(DN[1]+5),  (DM[2]+5)*TW+(DN[2]+5),
  (DM[3]+5)*TW+(DN[3]+5),  (DM[4]+5)*TW+(DN[4]+5),  (DM[5]+5)*TW+(DN[5]+5),
  (DM[6]+5)*TW+(DN[6]+5),  (DM[7]+5)*TW+(DN[7]+5),  (DM[8]+5)*TW+(DN[8]+5),
  (DM[9]+5)*TW+(DN[9]+5),  (DM[10]+5)*TW+(DN[10]+5),(DM[11]+5)*TW+(DN[11]+5),
  (DM[12]+5)*TW+(DN[12]+5),(DM[13]+5)*TW+(DN[13]+5),(DM[14]+5)*TW+(DN[14]+5),
  (DM[15]+5)*TW+(DN[15]+5),(DM[16]+5)*TW+(DN[16]+5),(DM[17]+5)*TW+(DN[17]+5),
  (DM[18]+5)*TW+(DN[18]+5),(DM[19]+5)*TW+(DN[19]+5),(DM[20]+5)*TW+(DN[20]+5),
  (DM[21]+5)*TW+(DN[21]+5),(DM[22]+5)*TW+(DN[22]+5),(DM[23]+5)*TW+(DN[23]+5),
  (DM[24]+5)*TW+(DN[24]+5),(DM[25]+5)*TW+(DN[25]+5),(DM[26]+5)*TW+(DN[26]+5),
  (DM[27]+5)*TW+(DN[27]+5),(DM[28]+5)*TW+(DN[28]+5),(DM[29]+5)*TW+(DN[29]+5),
  (DM[30]+5)*TW+(DN[30]+5)};
constexpr float COSC[NOFF] = {
  (DM[0]*DM[0]+DN[0]*DN[0])/40.0f,   (DM[1]*DM[1]+DN[1]*DN[1])/40.0f,
  (DM[2]*DM[2]+DN[2]*DN[2])/40.0f,   (DM[3]*DM[3]+DN[3]*DN[3])/40.0f,
  (DM[4]*DM[4]+DN[4]*DN[4])/40.0f,   (DM[5]*DM[5]+DN[5]*DN[5])/40.0f,
  (DM[6]*DM[6]+DN[6]*DN[6])/40.0f,   (DM[7]*DM[7]+DN[7]*DN[7])/40.0f,
  (DM[8]*DM[8]+DN[8]*DN[8])/40.0f,   (DM[9]*DM[9]+DN[9]*DN[9])/40.0f,
  (DM[10]*DM[10]+DN[10]*DN[10])/40.0f,(DM[11]*DM[11]+DN[11]*DN[11])/40.0f,
  (DM[12]*DM[12]+DN[12]*DN[12])/40.0f,(DM[13]*DM[13]+DN[13]*DN[13])/40.0f,
  (DM[14]*DM[14]+DN[14]*DN[14])/40.0f,(DM[15]*DM[15]+DN[15]*DN[15])/40.0f,
  (DM[16]*DM[16]+DN[16]*DN[16])/40.0f,(DM[17]*DM[17]+DN[17]*DN[17])/40.0f,
  (DM[18]*DM[18]+DN[18]*DN[18])/40.0f,(DM[19]*DM[19]+DN[19]*DN[19])/40.0f,
  (DM[20]*DM[20]+DN[20]*DN[20])/40.0f,(DM[21]*DM[21]+DN[21]*DN[21])/40.0f,
  (DM[22]*DM[22]+DN[22]*DN[22])/40.0f,(DM[23]*DM[23]+DN[23]*DN[23])/40.0f,
  (DM[24]*DM[24]+DN[24]*DN[24])/40.0f,(DM[25]*DM[25]+DN[25]*DN[25])/40.0f,
  (DM[26]*DM[26]+DN[26]*DN[26])/40.0f,(DM[27]*DM[27]+DN[27]*DN[27])/40.0f,
  (DM[28]*DM[28]+DN[28]*DN[28])/40.0f,(DM[29]*DM[29]+DN[29]*DN[29])/40.0f,
  (DM[30]*DM[30]+DN[30]*DN[30])/40.0f};
}

// ---------- K1a: per-(batch,slice) partial sums over x ----------
__global__ void ncuts_stats1(const float* __restrict__ x, float* __restrict__ part) {
  __shared__ float red[4][4];
  const int b = blockIdx.x;
  const int n = b >> 5, s = b & 31;          // SB = 32
  const int t = threadIdx.x;
  const int lane = t & 63, wv = t >> 6;
  const float* xb = x + n * 3 * NPIX;
  const int base = s * (NPIX / SB);          // 1568 per slice
  float a0 = 0.f, a1 = 0.f, a2 = 0.f, aq = 0.f;
  for (int i = t; i < NPIX / SB; i += 256) {
    const int p = base + i;
    float v0 = xb[p], v1 = xb[NPIX + p], v2 = xb[2 * NPIX + p];
    a0 += v0; a1 += v1; a2 += v2;
    aq = fmaf(v0, v0, fmaf(v1, v1, fmaf(v2, v2, aq)));
  }
  #pragma unroll
  for (int m = 1; m < 64; m <<= 1) {
    a0 += __shfl_xor(a0, m, 64); a1 += __shfl_xor(a1, m, 64);
    a2 += __shfl_xor(a2, m, 64); aq += __shfl_xor(aq, m, 64);
  }
  if (lane == 0) { red[wv][0] = a0; red[wv][1] = a1; red[wv][2] = a2; red[wv][3] = aq; }
  __syncthreads();
  if (t < 4) part[b * 4 + t] = red[0][t] + red[1][t] + red[2][t] + red[3][t];
}

// ---------- K1b: reduce slice partials -> S[n][3], s2[n] ----------
__global__ void ncuts_stats2(const float* __restrict__ part,
                             float* __restrict__ Sv, float* __restrict__ s2v) {
  const int t = threadIdx.x;
  if (t < NB * 4) {
    const int n = t >> 2, val = t & 3;
    float s = 0.f;
    #pragma unroll 4
    for (int i = 0; i < SB; ++i) s += part[(n * SB + i) * 4 + val];
    if (val < 3) Sv[n * 3 + val] = s; else s2v[n] = s;
  }
}

// ---------- K2: main tile kernel, 3 k-phases; seg split into two [676][4] LDS
// arrays so pixel stride is exactly 16B -> conflict-free b128 reads AND writes
// (R5: [pix][8] 32B stride = 4-way conflict, SQ_LDS_BANK_CONFLICT 15M cyc ~23% of dur).
__global__ __launch_bounds__(256, 4)
void ncuts_main(const float* __restrict__ seg, const float* __restrict__ x,
                const float* __restrict__ Sv, const float* __restrict__ s2v,
                float* __restrict__ pA, float* __restrict__ pV) {
  __shared__ __align__(16) float sSegA[TW*TW*4];   // [pix][k0..3],  10816 B
  __shared__ __align__(16) float sSegB[TW*TW*4];   // [pix][k4..7],  10816 B
  __shared__ __align__(16) float sXi[TW*TW*4];     // [pix][{x0,x1,x2,0}], 10816 B
  __shared__ float sRed[4][48];                    // 768 B (slots >=40 ignored)

  const int t = threadIdx.x;
  const int lane = t & 63, wv = t >> 6;
  const int tx = t & 15, ty = t >> 4;
  const int tcx = blockIdx.x, tcy = blockIdx.y, n = blockIdx.z;
  const int r0 = tcy * TILE - 5, c0 = tcx * TILE - 5;

  // ---- stage xi packed float4 (676 pixels) ----
  const float* xb = x + n * 3 * NPIX;
  for (int e = t; e < TW * TW; e += 256) {
    const int rr = e / TW, cc = e - rr * TW;
    const int gr = r0 + rr, gc = c0 + cc;
    float v0 = 0.f, v1 = 0.f, v2 = 0.f;
    if ((unsigned)gr < XD && (unsigned)gc < YD) {
      const int g = gr * YD + gc;
      v0 = xb[g]; v1 = xb[NPIX + g]; v2 = xb[2 * NPIX + g];
    }
    *reinterpret_cast<float4*>(&sXi[e * 4]) = make_float4(v0, v1, v2, 0.f);
  }

  // ---- phase-invariant pixel-slot decomposition for seg staging ----
  // thread t owns pixels {t, t+256, t+512(<676)}; hoists the /26 %26 divides
  // out of the phase loop (R5: staging addr math was ~38% of VALU).
  const float* sb = seg + n * KK * NPIX;
  const float* psb[3]; bool pok[3];
  #pragma unroll
  for (int s = 0; s < 3; ++s) {
    const int p = t + s * 256;
    const int rr = p / TW, cc = p - rr * TW;
    const int gr = r0 + rr, gc = c0 + cc;
    pok[s] = (p < TW * TW) && ((unsigned)gr < XD) && ((unsigned)gc < YD);
    psb[s] = sb + (gr * YD + gc);   // only dereferenced when pok[s]
  }

  const int xib = ty * TW + tx;                  // corner-based pixel index
  const int cen = xib + (5 * TW + 5);

  const float S0 = Sv[n*3+0], S1 = Sv[n*3+1], S2 = Sv[n*3+2], s2n = s2v[n];

  float xc0, xc1, xc2, temp;
  bool haveCenter = false;

  #pragma unroll 1
  for (int p = 0; p < NPH; ++p) {
    const int kbase = p * KPH;
    const int kcnt  = (p == NPH - 1) ? (KK - 2 * KPH) : KPH;   // 7,7,6

    __syncthreads();   // prior phase's sSeg reads done (p=0: xi staging ordered too)

    // stage this phase's k-planes: one pixel per thread-slot, 7 coalesced
    // global loads, two conflict-free b128 LDS writes.
    #pragma unroll
    for (int s = 0; s < 3; ++s) {
      const int pix = t + s * 256;
      if (pix < TW * TW) {
        float v[8];
        #pragma unroll
        for (int ks = 0; ks < 8; ++ks) v[ks] = 0.f;
        if (pok[s]) {
          #pragma unroll
          for (int ks = 0; ks < KPH; ++ks)
            if (ks < kcnt) v[ks] = psb[s][(kbase + ks) * NPIX];
        }
        *reinterpret_cast<float4*>(&sSegA[pix * 4]) = make_float4(v[0], v[1], v[2], v[3]);
        *reinterpret_cast<float4*>(&sSegB[pix * 4]) = make_float4(v[4], v[5], v[6], v[7]);
      }
    }
    __syncthreads();

    if (!haveCenter) {
      const float4 xc = *reinterpret_cast<const float4*>(&sXi[cen * 4]);
      xc0 = xc.x; xc1 = xc.y; xc2 = xc.z;
      const float sqc = xc0*xc0 + xc1*xc1 + xc2*xc2;
      temp = 50176.f * sqc - 2.f * (xc0*S0 + xc1*S1 + xc2*S2) + s2n;
      haveCenter = true;
    }

    float acc[8];
    #pragma unroll
    for (int k = 0; k < 8; ++k) acc[k] = 0.f;

    // unroll 2 (NOT full): full unroll spilled to scratch in R1 (646MB write traffic)
    #pragma unroll 2
    for (int o = 0; o < NOFF; ++o) {
      const int rof = ROFXI[o];
      const float4 xs = *reinterpret_cast<const float4*>(&sXi[(xib + rof) * 4]);
      const float d0 = xc0 - xs.x, d1 = xc1 - xs.y, d2 = xc2 - xs.z;
      const float w = COSC[o] * sqrtf(fmaf(d0, d0, fmaf(d1, d1, d2 * d2)));
      const float4 q0 = *reinterpret_cast<const float4*>(&sSegA[(xib + rof) * 4]);
      const float4 q1 = *reinterpret_cast<const float4*>(&sSegB[(xib + rof) * 4]);
      acc[0] = fmaf(w, q0.x, acc[0]); acc[1] = fmaf(w, q0.y, acc[1]);
      acc[2] = fmaf(w, q0.z, acc[2]); acc[3] = fmaf(w, q0.w, acc[3]);
      acc[4] = fmaf(w, q1.x, acc[4]); acc[5] = fmaf(w, q1.y, acc[5]);
      acc[6] = fmaf(w, q1.z, acc[6]); acc[7] = fmaf(w, q1.w, acc[7]);
    }

    // center seg for this phase's k's (pad slots are 0 -> contributions 0)
    const float4 c0v = *reinterpret_cast<const float4*>(&sSegA[cen * 4]);
    const float4 c1v = *reinterpret_cast<const float4*>(&sSegB[cen * 4]);
    const float segc[8] = {c0v.x, c0v.y, c0v.z, c0v.w, c1v.x, c1v.y, c1v.z, c1v.w};

    // packed butterfly: {pa,pv} x 2 kslots per pass; write at global-k slots.
    // Pad-k writes (value 0) land on slots later overwritten by the owning
    // phase (same-thread program order) or on slots >= 40 (ignored).
    #pragma unroll
    for (int pp = 0; pp < 4; ++pp) {
      const int s0i = 2 * pp, s1i = 2 * pp + 1;
      float pa0 = segc[s0i] * acc[s0i], pv0 = segc[s0i] * temp;
      float pa1 = segc[s1i] * acc[s1i], pv1 = segc[s1i] * temp;
      float s0 = (lane & 1) ? pv0 : pa0;
      float g0 = (lane & 1) ? pa0 : pv0;
      s0 += __shfl_xor(g0, 1, 64);
      float s1 = (lane & 1) ? pv1 : pa1;
      float g1 = (lane & 1) ? pa1 : pv1;
      s1 += __shfl_xor(g1, 1, 64);
      float cv = (lane & 2) ? s1 : s0;
      float gv = (lane & 2) ? s0 : s1;
      cv += __shfl_xor(gv, 2, 64);
      cv += __shfl_xor(cv, 4, 64);
      cv += __shfl_xor(cv, 8, 64);
      cv += __shfl_xor(cv, 16, 64);
      cv += __shfl_xor(cv, 32, 64);
      // lane 0: pa(k0g), lane 1: pv(k0g), lane 2: pa(k0g+1), lane 3: pv(k0g+1)
      const int k0g = kbase + 2 * pp;
      if (lane < 4) sRed[wv][2 * k0g + lane] = cv;
    }
  }

  __syncthreads();
  if (t < 2 * KK) {
    const float s = sRed[0][t] + sRed[1][t] + sRed[2][t] + sRed[3][t];
    const int tile = tcy * NT + tcx;
    const int k = t >> 1;
    float* dst = (t & 1) ? pV : pA;
    dst[tile * NKTOT + n * KK + k] = s;  // [tile][n*20+k], coalesced for K3
  }
}

// ---------- K3: reduce partials, form loss (1024 thr, 4 tile-groups) ----------
__global__ void ncuts_final(const float* __restrict__ pA, const float* __restrict__ pV,
                            float* __restrict__ out) {
  __shared__ float rA[4][NKTOT];
  __shared__ float rV[4][NKTOT];
  __shared__ float red[256];
  const int t = threadIdx.x;
  const int grp = t >> 8, i = t & 255;
  if (i < NKTOT) {
    float a = 0.f, v = 0.f;
    #pragma unroll 7
    for (int j = 0; j < NTILES / 4; ++j) {       // 49 tiles per group
      const int tile = grp * (NTILES / 4) + j;
      a += pA[tile * NKTOT + i];
      v += pV[tile * NKTOT + i];
    }
    rA[grp][i] = a; rV[grp][i] = v;
  }
  __syncthreads();
  if (t < 256) {
    float r = 0.f;
    if (t < NKTOT) {
      const float a = rA[0][t] + rA[1][t] + rA[2][t] + rA[3][t];
      const float v = rV[0][t] + rV[1][t] + rV[2][t] + rV[3][t];
      r = a / v;
    }
    red[t] = r;
  }
  __syncthreads();
  for (int s = 128; s > 0; s >>= 1) {
    if (t < s) red[t] += red[t + s];
    __syncthreads();
  }
  if (t == 0) out[0] = (float)NKTOT - red[0];
}

extern "C" void kernel_launch(void* const* d_in, const int* in_sizes, int n_in,
                              void* d_out, int out_size, void* d_ws, size_t ws_size,
                              hipStream_t stream) {
  const float* seg = (const float*)d_in[0];
  const float* x   = (const float*)d_in[1];
  float* ws   = (float*)d_ws;
  float* pA   = ws;                        // 31360 floats
  float* pV   = ws + NTILES * NKTOT;       // 31360 floats
  float* Sv   = ws + 2 * NTILES * NKTOT;   // 24
  float* s2v  = Sv + 24;                   // 8
  float* part = s2v + 8;                   // NB*SB*4 = 1024

  ncuts_stats1<<<NB * SB, 256, 0, stream>>>(x, part);
  ncuts_stats2<<<1, 64, 0, stream>>>(part, Sv, s2v);
  dim3 grid(NT, NT, NB);
  ncuts_main<<<grid, 256, 0, stream>>>(seg, x, Sv, s2v, pA, pV);
  ncuts_final<<<1, 1024, 0, stream>>>(pA, pV, (float*)d_out);
}

// Round 7
// 131.798 us; speedup vs baseline: 4.7936x; 1.1263x over previous
//
#include <hip/hip_runtime.h>

#define NB 8
#define KK 20
#define XD 224
#define YD 224
#define NPIX (XD*YD)        // 50176
#define TILE 16
#define NT 14               // 224/16
#define TW 26               // TILE + 2*5 halo
#define NOFF 31
#define NKTOT (NB*KK)       // 160
#define NTILES (NT*NT)      // 196
#define NPH 2               // k-phases (10 k's each, no tail)
#define KPH 10
#define SB 32               // stats slices per batch

namespace {
// offsets with sqrt(dm^2+dn^2) >= 5, dm,dn in [-5,4] (faithful to source)
constexpr int DM[NOFF] = {
  -5,-5,-5,-5,-5,-5,-5,-5,-5,-5,
  -4,-4,-4,-4,-4,
  -3,-3,-3,
  -2,-1, 0, 1, 2,
   3, 3, 3,
   4, 4, 4, 4, 4};
constexpr int DN[NOFF] = {
  -5,-4,-3,-2,-1, 0, 1, 2, 3, 4,
  -5,-4,-3, 3, 4,
  -5,-4, 4,
  -5,-5,-5,-5,-5,
  -5,-4, 4,
  -5,-4,-3, 3, 4};

constexpr int ROFXI[NOFF] = {
  (DM[0]+5)*TW+(DN[0]+5),  (DM[1]+5)*TW+(DN[1]+5),  (DM[2]+5)*TW+(DN[2]+5),
  (DM[3]+5)*TW+(DN[3]+5),  (DM[4]+5)*TW+(DN[4]+5),  (DM[5]+5)*TW+(DN[5]+5),
  (DM[6]+5)*TW+(DN[6]+5),  (DM[7]+5)*TW+(DN[7]+5),  (DM[8]+5)*TW+(DN[8]+5),
  (DM[9]+5)*TW+(DN[9]+5),  (DM[10]+5)*TW+(DN[10]+5),(DM[11]+5)*TW+(DN[11]+5),
  (DM[12]+5)*TW+(DN[12]+5),(DM[13]+5)*TW+(DN[13]+5),(DM[14]+5)*TW+(DN[14]+5),
  (DM[15]+5)*TW+(DN[15]+5),(DM[16]+5)*TW+(DN[16]+5),(DM[17]+5)*TW+(DN[17]+5),
  (DM[18]+5)*TW+(DN[18]+5),(DM[19]+5)*TW+(DN[19]+5),(DM[20]+5)*TW+(DN[20]+5),
  (DM[21]+5)*TW+(DN[21]+5),(DM[22]+5)*TW+(DN[22]+5),(DM[23]+5)*TW+(DN[23]+5),
  (DM[24]+5)*TW+(DN[24]+5),(DM[25]+5)*TW+(DN[25]+5),(DM[26]+5)*TW+(DN[26]+5),
  (DM[27]+5)*TW+(DN[27]+5),(DM[28]+5)*TW+(DN[28]+5),(DM[29]+5)*TW+(DN[29]+5),
  (DM[30]+5)*TW+(DN[30]+5)};
constexpr float COSC[NOFF] = {
  (DM[0]*DM[0]+DN[0]*DN[0])/40.0f,   (DM[1]*DM[1]+DN[1]*DN[1])/40.0f,
  (DM[2]*DM[2]+DN[2]*DN[2])/40.0f,   (DM[3]*DM[3]+DN[3]*DN[3])/40.0f,
  (DM[4]*DM[4]+DN[4]*DN[4])/40.0f,   (DM[5]*DM[5]+DN[5]*DN[5])/40.0f,
  (DM[6]*DM[6]+DN[6]*DN[6])/40.0f,   (DM[7]*DM[7]+DN[7]*DN[7])/40.0f,
  (DM[8]*DM[8]+DN[8]*DN[8])/40.0f,   (DM[9]*DM[9]+DN[9]*DN[9])/40.0f,
  (DM[10]*DM[10]+DN[10]*DN[10])/40.0f,(DM[11]*DM[11]+DN[11]*DN[11])/40.0f,
  (DM[12]*DM[12]+DN[12]*DN[12])/40.0f,(DM[13]*DM[13]+DN[13]*DN[13])/40.0f,
  (DM[14]*DM[14]+DN[14]*DN[14])/40.0f,(DM[15]*DM[15]+DN[15]*DN[15])/40.0f,
  (DM[16]*DM[16]+DN[16]*DN[16])/40.0f,(DM[17]*DM[17]+DN[17]*DN[17])/40.0f,
  (DM[18]*DM[18]+DN[18]*DN[18])/40.0f,(DM[19]*DM[19]+DN[19]*DN[19])/40.0f,
  (DM[20]*DM[20]+DN[20]*DN[20])/40.0f,(DM[21]*DM[21]+DN[21]*DN[21])/40.0f,
  (DM[22]*DM[22]+DN[22]*DN[22])/40.0f,(DM[23]*DM[23]+DN[23]*DN[23])/40.0f,
  (DM[24]*DM[24]+DN[24]*DN[24])/40.0f,(DM[25]*DM[25]+DN[25]*DN[25])/40.0f,
  (DM[26]*DM[26]+DN[26]*DN[26])/40.0f,(DM[27]*DM[27]+DN[27]*DN[27])/40.0f,
  (DM[28]*DM[28]+DN[28]*DN[28])/40.0f,(DM[29]*DM[29]+DN[29]*DN[29])/40.0f,
  (DM[30]*DM[30]+DN[30]*DN[30])/40.0f};
}

// ---------- K1a: per-(batch,slice) partial sums over x ----------
__global__ void ncuts_stats1(const float* __restrict__ x, float* __restrict__ part) {
  __shared__ float red[4][4];
  const int b = blockIdx.x;
  const int n = b >> 5, s = b & 31;          // SB = 32
  const int t = threadIdx.x;
  const int lane = t & 63, wv = t >> 6;
  const float* xb = x + n * 3 * NPIX;
  const int base = s * (NPIX / SB);          // 1568 per slice
  float a0 = 0.f, a1 = 0.f, a2 = 0.f, aq = 0.f;
  for (int i = t; i < NPIX / SB; i += 256) {
    const int p = base + i;
    float v0 = xb[p], v1 = xb[NPIX + p], v2 = xb[2 * NPIX + p];
    a0 += v0; a1 += v1; a2 += v2;
    aq = fmaf(v0, v0, fmaf(v1, v1, fmaf(v2, v2, aq)));
  }
  #pragma unroll
  for (int m = 1; m < 64; m <<= 1) {
    a0 += __shfl_xor(a0, m, 64); a1 += __shfl_xor(a1, m, 64);
    a2 += __shfl_xor(a2, m, 64); aq += __shfl_xor(aq, m, 64);
  }
  if (lane == 0) { red[wv][0] = a0; red[wv][1] = a1; red[wv][2] = a2; red[wv][3] = aq; }
  __syncthreads();
  if (t < 4) part[b * 4 + t] = red[0][t] + red[1][t] + red[2][t] + red[3][t];
}

// ---------- K1b: reduce slice partials -> S[n][3], s2[n] ----------
__global__ void ncuts_stats2(const float* __restrict__ part,
                             float* __restrict__ Sv, float* __restrict__ s2v) {
  const int t = threadIdx.x;
  if (t < NB * 4) {
    const int n = t >> 2, val = t & 3;
    float s = 0.f;
    #pragma unroll 4
    for (int i = 0; i < SB; ++i) s += part[(n * SB + i) * 4 + val];
    if (val < 3) Sv[n * 3 + val] = s; else s2v[n] = s;
  }
}

// ---------- K2: main tile kernel, 2 k-phases x 10 k's.
// Seg in A[676][4]+B[676][4]+C[676][2] (16B/16B/8B pixel stride, conflict-
// minimal). 2 phases instead of 3 (R6): xi re-reads and w recompute drop 33%,
// DS instr/wave 3348 -> ~2728 cyc. LDS 38.5KB keeps 4 blocks/CU.
__global__ __launch_bounds__(256, 4)
void ncuts_main(const float* __restrict__ seg, const float* __restrict__ x,
                const float* __restrict__ Sv, const float* __restrict__ s2v,
                float* __restrict__ pA, float* __restrict__ pV) {
  __shared__ __align__(16) float sSegA[TW*TW*4];   // [pix][k0..3],  10816 B
  __shared__ __align__(16) float sSegB[TW*TW*4];   // [pix][k4..7],  10816 B
  __shared__ __align__(16) float sSegC[TW*TW*2];   // [pix][k8..9],   5408 B
  __shared__ __align__(16) float sXi[TW*TW*4];     // [pix][{x0,x1,x2,0}], 10816 B
  __shared__ float sRed[4][2*KK];                  // 640 B

  const int t = threadIdx.x;
  const int lane = t & 63, wv = t >> 6;
  const int tx = t & 15, ty = t >> 4;
  const int tcx = blockIdx.x, tcy = blockIdx.y, n = blockIdx.z;
  const int r0 = tcy * TILE - 5, c0 = tcx * TILE - 5;

  // ---- stage xi packed float4 (676 pixels) ----
  const float* xb = x + n * 3 * NPIX;
  for (int e = t; e < TW * TW; e += 256) {
    const int rr = e / TW, cc = e - rr * TW;
    const int gr = r0 + rr, gc = c0 + cc;
    float v0 = 0.f, v1 = 0.f, v2 = 0.f;
    if ((unsigned)gr < XD && (unsigned)gc < YD) {
      const int g = gr * YD + gc;
      v0 = xb[g]; v1 = xb[NPIX + g]; v2 = xb[2 * NPIX + g];
    }
    *reinterpret_cast<float4*>(&sXi[e * 4]) = make_float4(v0, v1, v2, 0.f);
  }

  // ---- phase-invariant pixel-slot decomposition for seg staging ----
  const float* sb = seg + n * KK * NPIX;
  const float* psb[3]; bool pok[3];
  #pragma unroll
  for (int s = 0; s < 3; ++s) {
    const int p = t + s * 256;
    const int rr = p / TW, cc = p - rr * TW;
    const int gr = r0 + rr, gc = c0 + cc;
    pok[s] = (p < TW * TW) && ((unsigned)gr < XD) && ((unsigned)gc < YD);
    psb[s] = sb + (gr * YD + gc);   // only dereferenced when pok[s]
  }

  const int xib = ty * TW + tx;                  // corner-based pixel index
  const int cen = xib + (5 * TW + 5);

  const float S0 = Sv[n*3+0], S1 = Sv[n*3+1], S2 = Sv[n*3+2], s2n = s2v[n];

  __syncthreads();   // xi staging done
  const float4 xc = *reinterpret_cast<const float4*>(&sXi[cen * 4]);
  const float xc0 = xc.x, xc1 = xc.y, xc2 = xc.z;
  const float sqc = xc0*xc0 + xc1*xc1 + xc2*xc2;
  const float temp = 50176.f * sqc - 2.f * (xc0*S0 + xc1*S1 + xc2*S2) + s2n;

  #pragma unroll 1
  for (int p = 0; p < NPH; ++p) {
    const int kbase = p * KPH;

    __syncthreads();   // prior phase's sSeg reads done

    // stage this phase's 10 k-planes: one pixel per thread-slot,
    // 10 coalesced global loads, b128+b128+b64 conflict-free LDS writes.
    #pragma unroll
    for (int s = 0; s < 3; ++s) {
      const int pix = t + s * 256;
      if (pix < TW * TW) {
        float v[KPH];
        #pragma unroll
        for (int ks = 0; ks < KPH; ++ks) v[ks] = 0.f;
        if (pok[s]) {
          #pragma unroll
          for (int ks = 0; ks < KPH; ++ks) v[ks] = psb[s][(kbase + ks) * NPIX];
        }
        *reinterpret_cast<float4*>(&sSegA[pix * 4]) = make_float4(v[0], v[1], v[2], v[3]);
        *reinterpret_cast<float4*>(&sSegB[pix * 4]) = make_float4(v[4], v[5], v[6], v[7]);
        *reinterpret_cast<float2*>(&sSegC[pix * 2]) = make_float2(v[8], v[9]);
      }
    }
    __syncthreads();

    float acc[KPH];
    #pragma unroll
    for (int k = 0; k < KPH; ++k) acc[k] = 0.f;

    // unroll 2 (NOT full): full unroll spilled to scratch in R1 (646MB write traffic)
    #pragma unroll 2
    for (int o = 0; o < NOFF; ++o) {
      const int rof = ROFXI[o];
      const float4 xs = *reinterpret_cast<const float4*>(&sXi[(xib + rof) * 4]);
      const float d0 = xc0 - xs.x, d1 = xc1 - xs.y, d2 = xc2 - xs.z;
      const float dd = fmaf(d0, d0, fmaf(d1, d1, d2 * d2));
      // w = cosc * sqrt(dd): dd * rsqrt(dd) avoids the OCML sqrt sequence.
      const float w = COSC[o] * dd * __frsqrt_rn(fmaxf(dd, 1e-30f));
      const float4 q0 = *reinterpret_cast<const float4*>(&sSegA[(xib + rof) * 4]);
      const float4 q1 = *reinterpret_cast<const float4*>(&sSegB[(xib + rof) * 4]);
      const float2 q2 = *reinterpret_cast<const float2*>(&sSegC[(xib + rof) * 2]);
      acc[0] = fmaf(w, q0.x, acc[0]); acc[1] = fmaf(w, q0.y, acc[1]);
      acc[2] = fmaf(w, q0.z, acc[2]); acc[3] = fmaf(w, q0.w, acc[3]);
      acc[4] = fmaf(w, q1.x, acc[4]); acc[5] = fmaf(w, q1.y, acc[5]);
      acc[6] = fmaf(w, q1.z, acc[6]); acc[7] = fmaf(w, q1.w, acc[7]);
      acc[8] = fmaf(w, q2.x, acc[8]); acc[9] = fmaf(w, q2.y, acc[9]);
    }

    // center seg for this phase's k's
    const float4 c0v = *reinterpret_cast<const float4*>(&sSegA[cen * 4]);
    const float4 c1v = *reinterpret_cast<const float4*>(&sSegB[cen * 4]);
    const float2 c2v = *reinterpret_cast<const float2*>(&sSegC[cen * 2]);
    const float segc[KPH] = {c0v.x, c0v.y, c0v.z, c0v.w,
                             c1v.x, c1v.y, c1v.z, c1v.w, c2v.x, c2v.y};

    // packed butterfly: {pa,pv} x 2 k's per pass, 5 passes per phase.
    #pragma unroll
    for (int pp = 0; pp < KPH / 2; ++pp) {
      const int s0i = 2 * pp, s1i = 2 * pp + 1;
      float pa0 = segc[s0i] * acc[s0i], pv0 = segc[s0i] * temp;
      float pa1 = segc[s1i] * acc[s1i], pv1 = segc[s1i] * temp;
      float s0 = (lane & 1) ? pv0 : pa0;
      float g0 = (lane & 1) ? pa0 : pv0;
      s0 += __shfl_xor(g0, 1, 64);
      float s1 = (lane & 1) ? pv1 : pa1;
      float g1 = (lane & 1) ? pa1 : pv1;
      s1 += __shfl_xor(g1, 1, 64);
      float cv = (lane & 2) ? s1 : s0;
      float gv = (lane & 2) ? s0 : s1;
      cv += __shfl_xor(gv, 2, 64);
      cv += __shfl_xor(cv, 4, 64);
      cv += __shfl_xor(cv, 8, 64);
      cv += __shfl_xor(cv, 16, 64);
      cv += __shfl_xor(cv, 32, 64);
      // lane 0: pa(k0g), lane 1: pv(k0g), lane 2: pa(k0g+1), lane 3: pv(k0g+1)
      const int k0g = kbase + 2 * pp;
      if (lane < 4) sRed[wv][2 * k0g + lane] = cv;
    }
  }

  __syncthreads();
  if (t < 2 * KK) {
    const float s = sRed[0][t] + sRed[1][t] + sRed[2][t] + sRed[3][t];
    const int tile = tcy * NT + tcx;
    const int k = t >> 1;
    float* dst = (t & 1) ? pV : pA;
    dst[(n * KK + k) * NTILES + tile] = s;  // [nk][tile]: coalesced for final1
  }
}

// ---------- K3a: per-nk tile reduction (160 blocks x 64 thr) ----------
__global__ void ncuts_final1(const float* __restrict__ pA, const float* __restrict__ pV,
                             float* __restrict__ rA, float* __restrict__ rV) {
  const int nk = blockIdx.x, t = threadIdx.x;
  float a = 0.f, v = 0.f;
  for (int j = t; j < NTILES; j += 64) {
    a += pA[nk * NTILES + j];
    v += pV[nk * NTILES + j];
  }
  #pragma unroll
  for (int m = 1; m < 64; m <<= 1) {
    a += __shfl_xor(a, m, 64);
    v += __shfl_xor(v, m, 64);
  }
  if (t == 0) { rA[nk] = a; rV[nk] = v; }
}

// ---------- K3b: divide + sum -> loss ----------
__global__ void ncuts_final2(const float* __restrict__ rA, const float* __restrict__ rV,
                             float* __restrict__ out) {
  __shared__ float red[256];
  const int t = threadIdx.x;
  float r = 0.f;
  if (t < NKTOT) r = rA[t] / rV[t];
  red[t] = r;
  __syncthreads();
  for (int s = 128; s > 0; s >>= 1) {
    if (t < s) red[t] += red[t + s];
    __syncthreads();
  }
  if (t == 0) out[0] = (float)NKTOT - red[0];
}

extern "C" void kernel_launch(void* const* d_in, const int* in_sizes, int n_in,
                              void* d_out, int out_size, void* d_ws, size_t ws_size,
                              hipStream_t stream) {
  const float* seg = (const float*)d_in[0];
  const float* x   = (const float*)d_in[1];
  float* ws   = (float*)d_ws;
  float* pA   = ws;                        // 160*196 floats
  float* pV   = ws + NKTOT * NTILES;       // 160*196 floats
  float* Sv   = ws + 2 * NKTOT * NTILES;   // 24
  float* s2v  = Sv + 24;                   // 8
  float* part = s2v + 8;                   // NB*SB*4 = 1024
  float* rA   = part + 1024;               // 160
  float* rV   = rA + NKTOT;                // 160

  ncuts_stats1<<<NB * SB, 256, 0, stream>>>(x, part);
  ncuts_stats2<<<1, 64, 0, stream>>>(part, Sv, s2v);
  dim3 grid(NT, NT, NB);
  ncuts_main<<<grid, 256, 0, stream>>>(seg, x, Sv, s2v, pA, pV);
  ncuts_final1<<<NKTOT, 64, 0, stream>>>(pA, pV, rA, rV);
  ncuts_final2<<<1, 256, 0, stream>>>(rA, rV, (float*)d_out);
}